// Round 9
// baseline (580.629 us; speedup 1.0000x reference)
//
#include <hip/hip_runtime.h>

// Fake-quant (4-bit signed, symmetric) + bit-flip noise + dequant.
// Pure elementwise. HBM traffic already minimal (FETCH 256 MiB = L3-capacity
// floor + WRITE 256 MiB); gap to the ~90-120us roofline is request RATE.
//
// R6/R7 post-mortem: both batching attempts failed -- VGPR stayed 24 (can't
// hold 8x16B results), scheduler re-serialized loads despite sched_barrier.
// R8: force the batch with an empty asm volatile tying all 8 loaded vectors
// as "+v" operands -> all 8 values must be live in VGPRs simultaneously ->
// loads must all issue before any consumption. Diagnostic: VGPR must rise
// to >=56; if it does and time doesn't move, latency theory is refuted.
//
// inputs: d_in[0]=x f32[64M], d_in[1]=q_range f32[1], d_in[2]=epsilon i32[64M]

typedef float f32x4 __attribute__((ext_vector_type(4)));
typedef int   i32x4 __attribute__((ext_vector_type(4)));

#define BLOCK 256
#define TILE  (BLOCK * 4)   // f32x4 elements per block-tile (UNROLL=4)

__device__ __forceinline__ float qn_elem(float x, int e, float qr,
                                         float step, float inv_step) {
    float xc = fminf(fmaxf(x, -qr), qr);      // symmetric clip
    float xr = rintf(xc * inv_step);          // RNE, matches jnp.round
    xr = fminf(fmaxf(xr, -8.0f), 7.0f);       // clamp to [QN, QP]
    int u    = ((int)xr) & 15;                // int2bin (two's complement)
    int up   = u ^ e;                         // bit flips
    int pert = (up << 28) >> 28;              // bin2int: 4-bit sign extend
    return (float)pert * step;                // dequant
}

__device__ __forceinline__ f32x4 qn_vec4(f32x4 xv, i32x4 ev, float qr,
                                         float step, float inv_step) {
    f32x4 ov;
#pragma unroll
    for (int c = 0; c < 4; ++c)
        ov[c] = qn_elem(xv[c], ev[c], qr, step, inv_step);
    return ov;
}

__global__ __launch_bounds__(BLOCK) void WCAT_quantnoise_kernel(
    const f32x4* __restrict__ x4,
    const i32x4* __restrict__ e4,
    const float* __restrict__ q_range_p,
    f32x4* __restrict__ out4,
    int n4)
{
    const float qr       = q_range_p[0];
    const float step     = qr * 0.125f;       // qr / 2^(N_BITS-1), exact
    const float inv_step = 8.0f / qr;         // exact when qr is a power of 2

    const int tid    = threadIdx.x;
    const int ntiles = n4 / TILE;

    for (int t = blockIdx.x; t < ntiles; t += gridDim.x) {
        const int base = t * TILE + tid;

        // --- issue ALL 8 loads; the asm tie below forces all 8 results
        //     to be simultaneously live in VGPRs (32 data regs), so the
        //     compiler CANNOT re-serialize into load->compute->load. ---
        f32x4 xv0 = x4[base + 0 * BLOCK];
        f32x4 xv1 = x4[base + 1 * BLOCK];
        f32x4 xv2 = x4[base + 2 * BLOCK];
        f32x4 xv3 = x4[base + 3 * BLOCK];
        i32x4 ev0 = e4[base + 0 * BLOCK];
        i32x4 ev1 = e4[base + 1 * BLOCK];
        i32x4 ev2 = e4[base + 2 * BLOCK];
        i32x4 ev3 = e4[base + 3 * BLOCK];
        asm volatile("" : "+v"(xv0), "+v"(xv1), "+v"(xv2), "+v"(xv3),
                          "+v"(ev0), "+v"(ev1), "+v"(ev2), "+v"(ev3));

        out4[base + 0 * BLOCK] = qn_vec4(xv0, ev0, qr, step, inv_step);
        out4[base + 1 * BLOCK] = qn_vec4(xv1, ev1, qr, step, inv_step);
        out4[base + 2 * BLOCK] = qn_vec4(xv2, ev2, qr, step, inv_step);
        out4[base + 3 * BLOCK] = qn_vec4(xv3, ev3, qr, step, inv_step);
    }

    // tail (n4 not divisible by TILE) — not hit for 8192^2 but keep general
    for (int i = ntiles * TILE + blockIdx.x * BLOCK + tid; i < n4;
         i += gridDim.x * BLOCK) {
        out4[i] = qn_vec4(x4[i], e4[i], qr, step, inv_step);
    }
}

extern "C" void kernel_launch(void* const* d_in, const int* in_sizes, int n_in,
                              void* d_out, int out_size, void* d_ws, size_t ws_size,
                              hipStream_t stream) {
    const float* x       = (const float*)d_in[0];
    const float* q_range = (const float*)d_in[1];
    const int*   epsilon = (const int*)d_in[2];
    float*       out     = (float*)d_out;

    const int n  = in_sizes[0];       // 8192*8192
    const int n4 = n / 4;

    int grid = 2048;                  // 8 blocks/CU; grid-stride over tiles
    int ntiles = n4 / TILE;
    if (grid > ntiles && ntiles > 0) grid = ntiles;

    WCAT_quantnoise_kernel<<<grid, BLOCK, 0, stream>>>(
        (const f32x4*)x, (const i32x4*)epsilon, q_range, (f32x4*)out, n4);
}